// Round 13
// baseline (65.088 us; speedup 1.0000x reference)
//
#include <hip/hip_runtime.h>
#include <math.h>

// Problem constants
#define BATCH 64
#define HH 512
#define WW 512
#define PAD 15
#define NELEM ((size_t)BATCH * HH * WW)
#define INV_KK (1.0f / 961.0f)

#define THREADS 512            // 8 waves per block
#define TILE_H 32              // rows per block
#define RPI 8                  // rows per iteration (1 per wave)
#define NIT (TILE_H / RPI)     // 4 iterations
#define BPI (HH / TILE_H)      // 16 blocks per image
#define NBLK (BATCH * BPI)     // 1024 blocks -> 4 blocks/CU, 32 waves/CU
#define NXCD 8

typedef float f4 __attribute__((ext_vector_type(4)));

__device__ __forceinline__ float wave_reduce(float v) {
    #pragma unroll
    for (int off = 32; off; off >>= 1) v += __shfl_down(v, off, 64);
    return v;
}

// ---------------------------------------------------------------------------
// R11 structure scaled to 8 waves/block for max occupancy:
//  - 512 threads: producer owns ONE column each (prefetch regs halve to 16),
//    8 vertical-sum rows per iteration, wave wv scans+consumes row wv.
//  - in-place prefix scan (no separate P buffer): LDS = 32.9KB -> 4 blocks/CU
//    x 8 waves = 32 waves/CU (hw max; R11 had 16).
//  - register prefetch of next iteration's add/sub mask rows (R11-proven).
//  - double-buffered vrow, 1 barrier per 8 rows. Safety: every wave executes
//    loss(it) before producer(it+1) before barrier(it+1); producer(it+2)
//    reuses buffer (it&1) only after barrier(it+1) -> no wave can overwrite
//    a row another wave is still reading.
// ---------------------------------------------------------------------------
__global__ __launch_bounds__(THREADS) void fused_kernel(const float* __restrict__ pred,
                                                        const float* __restrict__ mask,
                                                        double* __restrict__ partials) {
    __shared__ float vrow[2][RPI][WW];   // double-buffered; prefix in place
    __shared__ float red[3][8];

    // XCD swizzle: xcd = f%8 (HW round-robin); each XCD owns 8 whole images.
    const int f    = blockIdx.x;
    const int xcd  = f & (NXCD - 1);
    const int slot = f >> 3;               // 0..127
    const int img  = xcd * 8 + (slot >> 4);
    const int tile = slot & (BPI - 1);

    const int tid  = threadIdx.x;          // 0..511
    const int lane = tid & 63;
    const int wv   = tid >> 6;             // 0..7
    const int h0   = tile * TILE_H;        // block's first output row (max 480)
    const int c    = tid;                  // producer column (1 per thread)

    const float* mb = mask + (size_t)img * HH * WW;
    const float* pb = pred + (size_t)img * HH * WW;

    // --- init rolling vertical window for row h0: rows [max(0,h0-15), min(511,h0+15)]
    float r = 0.0f;
    {
        int lo = h0 - PAD; if (lo < 0) lo = 0;
        int hi = h0 + PAD; if (hi > HH - 1) hi = HH - 1;
        for (int y = lo; y <= hi; ++y) r += mb[(size_t)y * WW + c];
    }

    // Prefetched add/sub rows for the upcoming iteration: emitting row h
    // slides +row(h+16) -row(h-15).
    float pa[RPI], ps[RPI];

    #define PREFETCH(ii)                                                   \
    {                                                                      \
        const int hb = h0 + RPI * (ii);                                    \
        _Pragma("unroll")                                                  \
        for (int j = 0; j < RPI; ++j) {                                    \
            const int ar = hb + 16 + j;                                    \
            const int sr = hb - 15 + j;                                    \
            pa[j] = (ar < HH) ? mb[(size_t)ar * WW + c] : 0.0f;            \
            ps[j] = (sr >= 0) ? mb[(size_t)sr * WW + c] : 0.0f;            \
        }                                                                  \
    }

    PREFETCH(0)

    float accb = 0.0f, acci = 0.0f, accu = 0.0f;

    #pragma unroll 1   // forbid outer unroll: protects the register budget
    for (int it = 0; it < NIT; ++it) {
        const int hbase = h0 + it * RPI;
        float (*vb)[WW] = vrow[it & 1];

        // --- producer: pure LDS/VALU, consumes prefetched rows ---
        #pragma unroll
        for (int j = 0; j < RPI; ++j) {
            vb[j][c] = r;
            r += pa[j] - ps[j];
        }
        __syncthreads();   // vb visible to all waves (the only barrier)

        // --- issue next iteration's mask loads (hide under scan+loss) ---
        if (it + 1 < NIT) PREFETCH(it + 1)

        // --- scan: wave wv prefix-scans row wv IN PLACE (wave-private) ---
        const int h = hbase + wv;
        const size_t rbase = (size_t)h * WW;
        float* row = vb[wv];

        f4 va = *(const f4*)&row[8 * lane];
        f4 vc = *(const f4*)&row[8 * lane + 4];
        float p0 = va.x;
        float p1 = p0 + va.y;
        float p2 = p1 + va.z;
        float p3 = p2 + va.w;
        float p4 = p3 + vc.x;
        float p5 = p4 + vc.y;
        float p6 = p5 + vc.z;
        float p7 = p6 + vc.w;
        float lanesum = p7;
        float incl = lanesum;
        #pragma unroll
        for (int off = 1; off < 64; off <<= 1) {
            float n = __shfl_up(incl, off, 64);
            if (lane >= off) incl += n;
        }
        const float excl = incl - lanesum;
        f4 Pa, Pb;
        Pa.x = excl + p0; Pa.y = excl + p1; Pa.z = excl + p2; Pa.w = excl + p3;
        Pb.x = excl + p4; Pb.y = excl + p5; Pb.z = excl + p6; Pb.w = excl + p7;
        *(f4*)&row[8 * lane]     = Pa;
        *(f4*)&row[8 * lane + 4] = Pb;
        // no barrier: row wv is consumed only by wave wv (same-wave DS order).

        // --- loss: lane owns w = lane + 64k of row hbase+wv ---
        #pragma unroll
        for (int k = 0; k < 8; ++k) {
            const int w = lane + 64 * k;
            int hiw = w + PAD; if (hiw > WW - 1) hiw = WW - 1;
            float s = row[hiw];
            if (w >= PAD + 1) s -= row[w - PAD - 1];

            const float m  = mb[rbase + w];
            const float pr = pb[rbase + w];

            const float weit = 1.0f + 5.0f * fabsf(s * INV_KK - m);
            const float e    = __expf(-fabsf(pr));
            const float bce  = fmaxf(pr, 0.0f) - pr * m + __logf(1.0f + e);
            const float inv  = __builtin_amdgcn_rcpf(1.0f + e);
            const float p    = (pr >= 0.0f) ? inv : e * inv;   // sigmoid(pr)

            accb += bce;
            acci += p * m * weit;
            accu += (p + m) * weit;
        }
        // no end barrier: vrow is double-buffered (safety argument above).
    }
    #undef PREFETCH

    // --- block reduction (8 waves) ---
    accb = wave_reduce(accb);
    acci = wave_reduce(acci);
    accu = wave_reduce(accu);
    if (lane == 0) { red[0][wv] = accb; red[1][wv] = acci; red[2][wv] = accu; }
    __syncthreads();
    if (tid == 0) {
        double bt = 0.0, it2 = 0.0, ut = 0.0;
        #pragma unroll
        for (int j = 0; j < 8; ++j) {
            bt += red[0][j]; it2 += red[1][j]; ut += red[2][j];
        }
        const size_t pidx = (size_t)img * BPI + tile;   // un-swizzled index
        partials[pidx * 3 + 0] = bt;
        partials[pidx * 3 + 1] = it2;
        partials[pidx * 3 + 2] = ut;
    }
}

// ---------------------------------------------------------------------------
// Finalize from per-block partials (indexed img*BPI + tile), NBLK = 1024.
// ---------------------------------------------------------------------------
__global__ __launch_bounds__(256) void finalize_kernel(const double* __restrict__ partials,
                                                       float* __restrict__ out) {
    __shared__ double redbce[4];
    int tid = threadIdx.x, lane = tid & 63, wv = tid >> 6;

    double bsum = 0.0;
    for (int i = tid; i < NBLK; i += 256) bsum += partials[(size_t)i * 3 + 0];
    #pragma unroll
    for (int off = 32; off; off >>= 1) bsum += __shfl_down(bsum, off, 64);
    if (lane == 0) redbce[wv] = bsum;
    __syncthreads();

    double wiou_term = 0.0;
    if (tid < 64) {
        int bb = tid;
        double it = 0.0, ut = 0.0;
        for (int j = 0; j < BPI; ++j) {
            it += partials[(size_t)(bb * BPI + j) * 3 + 1];
            ut += partials[(size_t)(bb * BPI + j) * 3 + 2];
        }
        wiou_term = 1.0 - (it + 1.0) / (ut - it + 1.0);
    }
    if (wv == 0) {
        #pragma unroll
        for (int off = 32; off; off >>= 1) wiou_term += __shfl_down(wiou_term, off, 64);
    }
    if (tid == 0) {
        double wbce = (redbce[0] + redbce[1] + redbce[2] + redbce[3]) / (double)NELEM;
        out[0] = (float)(wbce + wiou_term * (1.0 / 64.0));
    }
}

// ---------------------------------------------------------------------------
// Fallback path (tiny ws): recompute vertical sums in-kernel + atomics.
// ---------------------------------------------------------------------------
#define ACC_DOUBLES 129
__global__ __launch_bounds__(256) void rowpass_nows_kernel(const float* __restrict__ pred,
                                                           const float* __restrict__ mask,
                                                           double* __restrict__ acc) {
    __shared__ float vrow1[WW];
    __shared__ float red[3][4];
    int b = blockIdx.x / HH;
    int h = blockIdx.x % HH;
    int lo = h - PAD; if (lo < 0) lo = 0;
    int hi = h + PAD; if (hi > HH - 1) hi = HH - 1;
    float s0 = 0.0f, s1 = 0.0f;
    const float* mb = mask + (size_t)b * HH * WW;
    for (int y = lo; y <= hi; ++y) {
        s0 += mb[(size_t)y * WW + threadIdx.x];
        s1 += mb[(size_t)y * WW + threadIdx.x + 256];
    }
    vrow1[threadIdx.x]       = s0;
    vrow1[threadIdx.x + 256] = s1;
    __syncthreads();

    size_t base = ((size_t)b * HH + h) * WW;
    float bce_p = 0.0f, inter_p = 0.0f, uni_p = 0.0f;
    for (int w = threadIdx.x; w < WW; w += 256) {
        int wlo = w - PAD; if (wlo < 0) wlo = 0;
        int whi = w + PAD; if (whi > WW - 1) whi = WW - 1;
        float s = 0.0f;
        for (int k = wlo; k <= whi; ++k) s += vrow1[k];
        float m  = mask[base + w];
        float pr = pred[base + w];
        float weit = 1.0f + 5.0f * fabsf(s * INV_KK - m);
        float e   = expf(-fabsf(pr));
        float bce = fmaxf(pr, 0.0f) - pr * m + log1pf(e);
        float inv = 1.0f / (1.0f + e);
        float p   = (pr >= 0.0f) ? inv : e * inv;
        bce_p += bce; inter_p += p * m * weit; uni_p += (p + m) * weit;
    }
    int lane = threadIdx.x & 63, wvv = threadIdx.x >> 6;
    bce_p = wave_reduce(bce_p); inter_p = wave_reduce(inter_p); uni_p = wave_reduce(uni_p);
    if (lane == 0) { red[0][wvv] = bce_p; red[1][wvv] = inter_p; red[2][wvv] = uni_p; }
    __syncthreads();
    if (threadIdx.x == 0) {
        atomicAdd(&acc[0], (double)(red[0][0] + red[0][1] + red[0][2] + red[0][3]));
        atomicAdd(&acc[1 + b], (double)(red[1][0] + red[1][1] + red[1][2] + red[1][3]));
        atomicAdd(&acc[65 + b], (double)(red[2][0] + red[2][1] + red[2][2] + red[2][3]));
    }
}

__global__ void finalize_atomic_kernel(const double* __restrict__ acc, float* __restrict__ out) {
    int b = threadIdx.x;
    double inter = acc[1 + b];
    double uni   = acc[65 + b];
    double wiou = 1.0 - (inter + 1.0) / (uni - inter + 1.0);
    #pragma unroll
    for (int off = 32; off; off >>= 1) wiou += __shfl_down(wiou, off, 64);
    if (b == 0) {
        double wbce = acc[0] / (double)NELEM;
        out[0] = (float)(wbce + wiou * (1.0 / 64.0));
    }
}

// ---------------------------------------------------------------------------
extern "C" void kernel_launch(void* const* d_in, const int* in_sizes, int n_in,
                              void* d_out, int out_size, void* d_ws, size_t ws_size,
                              hipStream_t stream) {
    const float* pred = (const float*)d_in[0];
    const float* mask = (const float*)d_in[1];
    float* out = (float*)d_out;

    const size_t part_bytes = (size_t)NBLK * 3 * sizeof(double);   // 24 KiB

    if (ws_size >= part_bytes) {
        double* partials = (double*)d_ws;
        fused_kernel<<<NBLK, THREADS, 0, stream>>>(pred, mask, partials);
        finalize_kernel<<<1, 256, 0, stream>>>(partials, out);
    } else {
        double* acc = (double*)d_ws;
        hipMemsetAsync(acc, 0, ACC_DOUBLES * sizeof(double), stream);
        rowpass_nows_kernel<<<BATCH * HH, 256, 0, stream>>>(pred, mask, acc);
        finalize_atomic_kernel<<<1, 64, 0, stream>>>(acc, out);
    }
}

// Round 14
// 61.663 us; speedup vs baseline: 1.0556x; 1.0556x over previous
//
#include <hip/hip_runtime.h>
#include <math.h>

// Problem constants
#define BATCH 64
#define HH 512
#define WW 512
#define PAD 15
#define NELEM ((size_t)BATCH * HH * WW)
#define INV_KK (1.0f / 961.0f)

#define TILE_H 32              // rows per block
#define RPI 4                  // rows per iteration (1 per wave, 4 waves)
#define NIT (TILE_H / RPI)     // 8 iterations
#define BPI (HH / TILE_H)      // 16 blocks per image
#define NBLK (BATCH * BPI)     // 1024 blocks -> 4 blocks/CU
#define NXCD 8

typedef float f4 __attribute__((ext_vector_type(4)));

__device__ __forceinline__ float wave_reduce(float v) {
    #pragma unroll
    for (int off = 32; off; off >>= 1) v += __shfl_down(v, off, 64);
    return v;
}

// ---------------------------------------------------------------------------
// R11 (51.5us champion) + ONE isolated change: the loss-phase mask/pred rows
// are register-prefetched one iteration ahead (mn/pn), exactly like R11's
// add/sub slide rows. The cold pred HBM load (~900cy) now has a full
// iteration of producer+scan+loss to land instead of stalling after the scan.
// Double register sets + unroll-by-2 loop keep all indices static (no
// scratch). Everything else is bit-identical to R11.
// ---------------------------------------------------------------------------
__device__ __forceinline__ void iter_body(
    int it, int h0, int lane, int wv, int c0, int c1,
    float& r0, float& r1,
    float (&pa)[RPI], float (&ps)[RPI], float (&qa)[RPI], float (&qs)[RPI],
    float (&mc)[8], float (&pc)[8], float (&mn)[8], float (&pn)[8],
    const float* __restrict__ mb, const float* __restrict__ pb,
    float (*vb)[WW], float* __restrict__ Prow,
    float& accb, float& acci, float& accu)
{
    // --- producer: pure LDS/VALU, consumes prefetched slide rows ---
    #pragma unroll
    for (int j = 0; j < RPI; ++j) {
        vb[j][c0] = r0;
        vb[j][c1] = r1;
        r0 += pa[j] - ps[j];
        r1 += qa[j] - qs[j];
    }
    __syncthreads();   // vb visible to all waves (the only barrier)

    // --- issue next iteration's loads; latency hides under scan+loss ---
    if (it + 1 < NIT) {
        const int hb = h0 + RPI * (it + 1);
        #pragma unroll
        for (int j = 0; j < RPI; ++j) {
            const int ar = hb + 16 + j;
            const int sr = hb - 15 + j;
            pa[j] = (ar < HH) ? mb[(size_t)ar * WW + c0] : 0.0f;
            qa[j] = (ar < HH) ? mb[(size_t)ar * WW + c1] : 0.0f;
            ps[j] = (sr >= 0) ? mb[(size_t)sr * WW + c0] : 0.0f;
            qs[j] = (sr >= 0) ? mb[(size_t)sr * WW + c1] : 0.0f;
        }
        // next iteration's loss-row inputs for THIS wave (the new change)
        const size_t rbn = (size_t)(hb + wv) * WW;
        #pragma unroll
        for (int k = 0; k < 8; ++k) {
            mn[k] = mb[rbn + lane + 64 * k];
            pn[k] = pb[rbn + lane + 64 * k];
        }
    }

    // --- scan: wave wv prefix-scans vb[wv] into Prow (wave-private) ---
    f4 va = *(const f4*)&vb[wv][8 * lane];
    f4 vc = *(const f4*)&vb[wv][8 * lane + 4];
    float p0 = va.x;
    float p1 = p0 + va.y;
    float p2 = p1 + va.z;
    float p3 = p2 + va.w;
    float p4 = p3 + vc.x;
    float p5 = p4 + vc.y;
    float p6 = p5 + vc.z;
    float p7 = p6 + vc.w;
    float lanesum = p7;
    float incl = lanesum;
    #pragma unroll
    for (int off = 1; off < 64; off <<= 1) {
        float n = __shfl_up(incl, off, 64);
        if (lane >= off) incl += n;
    }
    const float excl = incl - lanesum;
    f4 Pa, Pb;
    Pa.x = excl + p0; Pa.y = excl + p1; Pa.z = excl + p2; Pa.w = excl + p3;
    Pb.x = excl + p4; Pb.y = excl + p5; Pb.z = excl + p6; Pb.w = excl + p7;
    *(f4*)&Prow[8 * lane]     = Pa;
    *(f4*)&Prow[8 * lane + 4] = Pb;
    // no barrier: Prow is wave-private (same-wave DS ordering).

    // --- loss: lane owns w = lane + 64k; inputs already in registers ---
    #pragma unroll
    for (int k = 0; k < 8; ++k) {
        const int w = lane + 64 * k;
        int hiw = w + PAD; if (hiw > WW - 1) hiw = WW - 1;
        float s = Prow[hiw];
        if (w >= PAD + 1) s -= Prow[w - PAD - 1];

        const float m  = mc[k];
        const float pr = pc[k];

        const float weit = 1.0f + 5.0f * fabsf(s * INV_KK - m);
        const float e    = __expf(-fabsf(pr));
        const float bce  = fmaxf(pr, 0.0f) - pr * m + __logf(1.0f + e);
        const float inv  = __builtin_amdgcn_rcpf(1.0f + e);
        const float p    = (pr >= 0.0f) ? inv : e * inv;   // sigmoid(pr)

        accb += bce;
        acci += p * m * weit;
        accu += (p + m) * weit;
    }
    // no end barrier: vrow is double-buffered (R11 safety argument).
}

__global__ __launch_bounds__(256) void fused_kernel(const float* __restrict__ pred,
                                                    const float* __restrict__ mask,
                                                    double* __restrict__ partials) {
    __shared__ float vrow[2][RPI][WW];   // double-buffered vertical-sum rows
    __shared__ float P[4][WW];           // per-wave private prefix rows
    __shared__ float red[3][4];

    // XCD swizzle: xcd = f%8 (HW round-robin); each XCD owns 8 whole images.
    const int f    = blockIdx.x;
    const int xcd  = f & (NXCD - 1);
    const int slot = f >> 3;               // 0..127
    const int img  = xcd * 8 + (slot >> 4);
    const int tile = slot & (BPI - 1);

    const int tid  = threadIdx.x;
    const int lane = tid & 63;
    const int wv   = tid >> 6;
    const int h0   = tile * TILE_H;        // block's first output row (max 480)
    const int c0   = tid;                  // producer columns
    const int c1   = tid + 256;

    const float* mb = mask + (size_t)img * HH * WW;
    const float* pb = pred + (size_t)img * HH * WW;

    // --- init rolling vertical window for row h0: rows [max(0,h0-15), min(511,h0+15)]
    float r0 = 0.0f, r1 = 0.0f;
    {
        int lo = h0 - PAD; if (lo < 0) lo = 0;
        int hi = h0 + PAD; if (hi > HH - 1) hi = HH - 1;
        for (int y = lo; y <= hi; ++y) {
            r0 += mb[(size_t)y * WW + c0];
            r1 += mb[(size_t)y * WW + c1];
        }
    }

    // prefetch registers
    float pa[RPI], ps[RPI], qa[RPI], qs[RPI];
    float mc[8], pc[8], mn[8], pn[8];

    // --- initial prefetch for iteration 0 ---
    {
        const int hb = h0;
        #pragma unroll
        for (int j = 0; j < RPI; ++j) {
            const int ar = hb + 16 + j;
            const int sr = hb - 15 + j;
            pa[j] = (ar < HH) ? mb[(size_t)ar * WW + c0] : 0.0f;
            qa[j] = (ar < HH) ? mb[(size_t)ar * WW + c1] : 0.0f;
            ps[j] = (sr >= 0) ? mb[(size_t)sr * WW + c0] : 0.0f;
            qs[j] = (sr >= 0) ? mb[(size_t)sr * WW + c1] : 0.0f;
        }
        const size_t rb0 = (size_t)(h0 + wv) * WW;
        #pragma unroll
        for (int k = 0; k < 8; ++k) {
            mc[k] = mb[rb0 + lane + 64 * k];
            pc[k] = pb[rb0 + lane + 64 * k];
        }
    }

    float accb = 0.0f, acci = 0.0f, accu = 0.0f;

    #pragma unroll 1   // two bodies per trip; forbid further unrolling
    for (int i2 = 0; i2 < NIT / 2; ++i2) {
        iter_body(2 * i2,     h0, lane, wv, c0, c1, r0, r1,
                  pa, ps, qa, qs, mc, pc, mn, pn,
                  mb, pb, vrow[0], P[wv], accb, acci, accu);
        iter_body(2 * i2 + 1, h0, lane, wv, c0, c1, r0, r1,
                  pa, ps, qa, qs, mn, pn, mc, pc,
                  mb, pb, vrow[1], P[wv], accb, acci, accu);
    }

    // --- block reduction ---
    accb = wave_reduce(accb);
    acci = wave_reduce(acci);
    accu = wave_reduce(accu);
    if (lane == 0) { red[0][wv] = accb; red[1][wv] = acci; red[2][wv] = accu; }
    __syncthreads();
    if (tid == 0) {
        double bt = (double)red[0][0] + red[0][1] + red[0][2] + red[0][3];
        double it2 = (double)red[1][0] + red[1][1] + red[1][2] + red[1][3];
        double ut = (double)red[2][0] + red[2][1] + red[2][2] + red[2][3];
        const size_t pidx = (size_t)img * BPI + tile;   // un-swizzled index
        partials[pidx * 3 + 0] = bt;
        partials[pidx * 3 + 1] = it2;
        partials[pidx * 3 + 2] = ut;
    }
}

// ---------------------------------------------------------------------------
// Finalize from per-block partials (indexed img*BPI + tile), NBLK = 1024.
// ---------------------------------------------------------------------------
__global__ __launch_bounds__(256) void finalize_kernel(const double* __restrict__ partials,
                                                       float* __restrict__ out) {
    __shared__ double redbce[4];
    int tid = threadIdx.x, lane = tid & 63, wv = tid >> 6;

    double bsum = 0.0;
    for (int i = tid; i < NBLK; i += 256) bsum += partials[(size_t)i * 3 + 0];
    #pragma unroll
    for (int off = 32; off; off >>= 1) bsum += __shfl_down(bsum, off, 64);
    if (lane == 0) redbce[wv] = bsum;
    __syncthreads();

    double wiou_term = 0.0;
    if (tid < 64) {
        int bb = tid;
        double it = 0.0, ut = 0.0;
        for (int j = 0; j < BPI; ++j) {
            it += partials[(size_t)(bb * BPI + j) * 3 + 1];
            ut += partials[(size_t)(bb * BPI + j) * 3 + 2];
        }
        wiou_term = 1.0 - (it + 1.0) / (ut - it + 1.0);
    }
    if (wv == 0) {
        #pragma unroll
        for (int off = 32; off; off >>= 1) wiou_term += __shfl_down(wiou_term, off, 64);
    }
    if (tid == 0) {
        double wbce = (redbce[0] + redbce[1] + redbce[2] + redbce[3]) / (double)NELEM;
        out[0] = (float)(wbce + wiou_term * (1.0 / 64.0));
    }
}

// ---------------------------------------------------------------------------
// Fallback path (tiny ws): recompute vertical sums in-kernel + atomics.
// ---------------------------------------------------------------------------
#define ACC_DOUBLES 129
__global__ __launch_bounds__(256) void rowpass_nows_kernel(const float* __restrict__ pred,
                                                           const float* __restrict__ mask,
                                                           double* __restrict__ acc) {
    __shared__ float vrow1[WW];
    __shared__ float red[3][4];
    int b = blockIdx.x / HH;
    int h = blockIdx.x % HH;
    int lo = h - PAD; if (lo < 0) lo = 0;
    int hi = h + PAD; if (hi > HH - 1) hi = HH - 1;
    float s0 = 0.0f, s1 = 0.0f;
    const float* mb = mask + (size_t)b * HH * WW;
    for (int y = lo; y <= hi; ++y) {
        s0 += mb[(size_t)y * WW + threadIdx.x];
        s1 += mb[(size_t)y * WW + threadIdx.x + 256];
    }
    vrow1[threadIdx.x]       = s0;
    vrow1[threadIdx.x + 256] = s1;
    __syncthreads();

    size_t base = ((size_t)b * HH + h) * WW;
    float bce_p = 0.0f, inter_p = 0.0f, uni_p = 0.0f;
    for (int w = threadIdx.x; w < WW; w += 256) {
        int wlo = w - PAD; if (wlo < 0) wlo = 0;
        int whi = w + PAD; if (whi > WW - 1) whi = WW - 1;
        float s = 0.0f;
        for (int k = wlo; k <= whi; ++k) s += vrow1[k];
        float m  = mask[base + w];
        float pr = pred[base + w];
        float weit = 1.0f + 5.0f * fabsf(s * INV_KK - m);
        float e   = expf(-fabsf(pr));
        float bce = fmaxf(pr, 0.0f) - pr * m + log1pf(e);
        float inv = 1.0f / (1.0f + e);
        float p   = (pr >= 0.0f) ? inv : e * inv;
        bce_p += bce; inter_p += p * m * weit; uni_p += (p + m) * weit;
    }
    int lane = threadIdx.x & 63, wvv = threadIdx.x >> 6;
    bce_p = wave_reduce(bce_p); inter_p = wave_reduce(inter_p); uni_p = wave_reduce(uni_p);
    if (lane == 0) { red[0][wvv] = bce_p; red[1][wvv] = inter_p; red[2][wvv] = uni_p; }
    __syncthreads();
    if (threadIdx.x == 0) {
        atomicAdd(&acc[0], (double)(red[0][0] + red[0][1] + red[0][2] + red[0][3]));
        atomicAdd(&acc[1 + b], (double)(red[1][0] + red[1][1] + red[1][2] + red[1][3]));
        atomicAdd(&acc[65 + b], (double)(red[2][0] + red[2][1] + red[2][2] + red[2][3]));
    }
}

__global__ void finalize_atomic_kernel(const double* __restrict__ acc, float* __restrict__ out) {
    int b = threadIdx.x;
    double inter = acc[1 + b];
    double uni   = acc[65 + b];
    double wiou = 1.0 - (inter + 1.0) / (uni - inter + 1.0);
    #pragma unroll
    for (int off = 32; off; off >>= 1) wiou += __shfl_down(wiou, off, 64);
    if (b == 0) {
        double wbce = acc[0] / (double)NELEM;
        out[0] = (float)(wbce + wiou * (1.0 / 64.0));
    }
}

// ---------------------------------------------------------------------------
extern "C" void kernel_launch(void* const* d_in, const int* in_sizes, int n_in,
                              void* d_out, int out_size, void* d_ws, size_t ws_size,
                              hipStream_t stream) {
    const float* pred = (const float*)d_in[0];
    const float* mask = (const float*)d_in[1];
    float* out = (float*)d_out;

    const size_t part_bytes = (size_t)NBLK * 3 * sizeof(double);   // 24 KiB

    if (ws_size >= part_bytes) {
        double* partials = (double*)d_ws;
        fused_kernel<<<NBLK, 256, 0, stream>>>(pred, mask, partials);
        finalize_kernel<<<1, 256, 0, stream>>>(partials, out);
    } else {
        double* acc = (double*)d_ws;
        hipMemsetAsync(acc, 0, ACC_DOUBLES * sizeof(double), stream);
        rowpass_nows_kernel<<<BATCH * HH, 256, 0, stream>>>(pred, mask, acc);
        finalize_atomic_kernel<<<1, 64, 0, stream>>>(acc, out);
    }
}